// Round 3
// baseline (13423.866 us; speedup 1.0000x reference)
//
#include <hip/hip_runtime.h>
#include <hip/hip_bf16.h>
#include <math.h>
#include <stdint.h>

// RNN LM forward: B=64 T=512 V=8192 E=1024 H=2048
// out = [logits (B*T*V f32) | loss (1 f32)]
#define Bb 64
#define Tt 512
#define Vv 8192
#define Ee 1024
#define Hh 2048

typedef unsigned short u16;
typedef unsigned long long u64;
typedef __attribute__((ext_vector_type(8))) short bf16x8;   // 8 bf16 = 4 VGPR (MFMA A/B frag)
typedef __attribute__((ext_vector_type(4))) float f32x4;    // MFMA C/D frag

__device__ __forceinline__ u16 f2b(float f) {               // f32 -> bf16 RNE
  unsigned u = __float_as_uint(f);
  u += 0x7FFF + ((u >> 16) & 1);
  return (u16)(u >> 16);
}
__device__ __forceinline__ float b2f(u16 h) {
  return __uint_as_float(((unsigned)h) << 16);
}
__device__ __forceinline__ bf16x8 comb(u64 a, u64 b) {
  union { u64 q[2]; bf16x8 v; } u;
  u.q[0] = a; u.q[1] = b; return u.v;
}
__device__ __forceinline__ u64 pack4(u16 a, u16 b, u16 c, u16 d) {
  return (u64)a | ((u64)b << 16) | ((u64)c << 32) | ((u64)d << 48);
}

__device__ __forceinline__ void gll16(const u16* g, u16* l) {
  __builtin_amdgcn_global_load_lds((__attribute__((address_space(1))) void*)g,
                                   (__attribute__((address_space(3))) void*)l, 16, 0, 0);
}

__device__ __forceinline__ float wave_max(float v) {
  #pragma unroll
  for (int d = 32; d; d >>= 1) v = fmaxf(v, __shfl_xor(v, d, 64));
  return v;
}
__device__ __forceinline__ float wave_sum(float v) {
  #pragma unroll
  for (int d = 32; d; d >>= 1) v += __shfl_xor(v, d, 64);
  return v;
}

// ---------------- prep kernels ----------------

// gather W_E rows by idx, split into bf16 hi|lo halves along K: emb2[m] = [hi(1024) | lo(1024)]
__global__ __launch_bounds__(256)
void embed_cast(const float* __restrict__ WE, const int* __restrict__ idx,
                u16* __restrict__ emb2) {
  const int m = blockIdx.x;
  const int row = idx[m];
  const float4 v = ((const float4*)(WE + (size_t)row * Ee))[threadIdx.x];
  ushort4 hi, lo;
  hi.x = f2b(v.x); lo.x = f2b(v.x - b2f(hi.x));
  hi.y = f2b(v.y); lo.y = f2b(v.y - b2f(hi.y));
  hi.z = f2b(v.z); lo.z = f2b(v.z - b2f(hi.z));
  hi.w = f2b(v.w); lo.w = f2b(v.w - b2f(hi.w));
  u16* d = emb2 + (size_t)m * 2048;
  ((ushort4*)d)[threadIdx.x] = hi;
  ((ushort4*)(d + Ee))[threadIdx.x] = lo;
}

// src[R][C] f32 -> dst[C][R<<dup] bf16 (transpose+cast hi); if dup, duplicate: [v | v]
__global__ __launch_bounds__(256)
void transpose_cast(const float* __restrict__ src, u16* __restrict__ dst,
                    int R, int C, int dup) {
  __shared__ float tile[32][33];
  const int bi = blockIdx.x;  // along C
  const int bj = blockIdx.y;  // along R
  const int tid = threadIdx.x;
  const int r  = tid >> 3;
  const int c4 = (tid & 7) * 4;
  float4 v = *(const float4*)(src + (size_t)(bj * 32 + r) * C + bi * 32 + c4);
  tile[r][c4 + 0] = v.x; tile[r][c4 + 1] = v.y;
  tile[r][c4 + 2] = v.z; tile[r][c4 + 3] = v.w;
  __syncthreads();
  const int RL = R << dup;
  ushort4 o;
  o.x = f2b(tile[c4 + 0][r]); o.y = f2b(tile[c4 + 1][r]);
  o.z = f2b(tile[c4 + 2][r]); o.w = f2b(tile[c4 + 3][r]);
  u16* d = dst + (size_t)(bi * 32 + r) * RL + bj * 32 + c4;
  *(ushort4*)d = o;
  if (dup) *(ushort4*)(d + R) = o;
}

// src[R][C] f32 -> hi[C][R], lo[C][R] bf16 (transpose + hi/lo split)
__global__ __launch_bounds__(256)
void transpose_cast_hilo(const float* __restrict__ src, u16* __restrict__ dhi,
                         u16* __restrict__ dlo, int R, int C) {
  __shared__ float tile[32][33];
  const int bi = blockIdx.x;  // along C
  const int bj = blockIdx.y;  // along R
  const int tid = threadIdx.x;
  const int r  = tid >> 3;
  const int c4 = (tid & 7) * 4;
  float4 v = *(const float4*)(src + (size_t)(bj * 32 + r) * C + bi * 32 + c4);
  tile[r][c4 + 0] = v.x; tile[r][c4 + 1] = v.y;
  tile[r][c4 + 2] = v.z; tile[r][c4 + 3] = v.w;
  __syncthreads();
  ushort4 oh, ol;
  #pragma unroll
  for (int j = 0; j < 4; ++j) {
    float x = tile[c4 + j][r];
    u16 h = f2b(x);
    ((u16*)&oh)[j] = h;
    ((u16*)&ol)[j] = f2b(x - b2f(h));
  }
  size_t off = (size_t)(bi * 32 + r) * R + bj * 32 + c4;
  *(ushort4*)(dhi + off) = oh;
  *(ushort4*)(dlo + off) = ol;
}

// h0[b] = [hi(start) | lo(start)] per batch row
__global__ __launch_bounds__(256)
void h0_init(const float* __restrict__ start, u16* __restrict__ hbuf) {
  const int b = blockIdx.x;
  #pragma unroll
  for (int j = 0; j < 8; ++j) {
    int n = threadIdx.x * 8 + j;
    float x = start[n];
    u16 hi = f2b(x);
    u16 lo = f2b(x - b2f(hi));
    hbuf[(size_t)b * 4096 + n] = hi;
    hbuf[(size_t)b * 4096 + 2048 + n] = lo;
  }
}

// ---------------- GEMM (m97-style 128x128 tile, BK=32, 4 waves) ----------------
// C[M x N] = A[M x K] * Bt[N x K]^T, bf16 inputs, f32 accum.
// MODE 0: out f32 at [row*N+col] + bias   (head GEMM -> logits in d_out)
// MODE 1: out bf16 at [(t*B+b)*N+col] + bias, row = b*T+t  (xproj, t-major)
// XCD-aware block swizzle (T1): nwg % 8 == 0 for both call sites.
template <int MODE>
__global__ __launch_bounds__(256, 2)
void gemm_bt(const u16* __restrict__ A, const u16* __restrict__ Bt,
             const float* __restrict__ bias, void* __restrict__ outp,
             int M, int N, int K) {
  __shared__ u16 ldsA[128 * 32];
  __shared__ u16 ldsB[128 * 32];
  const int tid = threadIdx.x;
  const int lane = tid & 63;
  const int w = tid >> 6;
  const int wr = w >> 1, wc = w & 1;

  const int nwg = gridDim.x * gridDim.y;
  const int lin = blockIdx.y * gridDim.x + blockIdx.x;
  const int swz = (lin & 7) * (nwg >> 3) + (lin >> 3);
  const int bm = swz % gridDim.x;
  const int bn = swz / gridDim.x;

  const int srow = w * 32 + (lane >> 2);
  const int scol = (lane & 3) * 8;
  const u16* a0 = A + (size_t)(bm * 128 + srow) * K + scol;
  const u16* b0 = Bt + (size_t)(bn * 128 + srow) * K + scol;
  u16* lA0 = ldsA + w * 1024;
  u16* lA1 = ldsA + w * 1024 + 512;
  u16* lB0 = ldsB + w * 1024;
  u16* lB1 = ldsB + w * 1024 + 512;

  f32x4 acc[4][4];
  #pragma unroll
  for (int m = 0; m < 4; ++m)
    #pragma unroll
    for (int n = 0; n < 4; ++n)
      acc[m][n] = (f32x4){0.f, 0.f, 0.f, 0.f};

  const int nk = K >> 5;
  for (int kt = 0; kt < nk; ++kt) {
    __syncthreads();
    const u16* ak = a0 + kt * 32;
    const u16* bk = b0 + kt * 32;
    gll16(ak, lA0);
    gll16(ak + 16 * (size_t)K, lA1);
    gll16(bk, lB0);
    gll16(bk + 16 * (size_t)K, lB1);
    __syncthreads();
    bf16x8 af[4], bfr[4];
    #pragma unroll
    for (int i = 0; i < 4; ++i) {
      af[i]  = *(const bf16x8*)&ldsA[(wr * 64 + i * 16 + (lane & 15)) * 32 + (lane >> 4) * 8];
      bfr[i] = *(const bf16x8*)&ldsB[(wc * 64 + i * 16 + (lane & 15)) * 32 + (lane >> 4) * 8];
    }
    #pragma unroll
    for (int m = 0; m < 4; ++m)
      #pragma unroll
      for (int n = 0; n < 4; ++n)
        acc[m][n] = __builtin_amdgcn_mfma_f32_16x16x32_bf16(af[m], bfr[n], acc[m][n], 0, 0, 0);
  }

  const int r0 = bm * 128 + wr * 64 + (lane >> 4) * 4;
  const int c0 = bn * 128 + wc * 64 + (lane & 15);
  #pragma unroll
  for (int n = 0; n < 4; ++n) {
    const int col = c0 + n * 16;
    const float bv = bias[col];
    #pragma unroll
    for (int m = 0; m < 4; ++m) {
      #pragma unroll
      for (int q = 0; q < 4; ++q) {
        const int row = r0 + m * 16 + q;
        float v = acc[m][n][q] + bv;
        if (MODE == 0) {
          ((float*)outp)[(size_t)row * N + col] = v;
        } else {
          const int b = row >> 9, t = row & 511;   // row = b*T + t
          ((u16*)outp)[((size_t)t * Bb + b) * N + col] = f2b(v);
        }
      }
    }
  }
}

// ---------------- persistent recurrence scan ----------------
// 256 blocks x 512 thr (8 waves), 1 block/CU (145KB LDS).
// Block bid: group g = bid>>6 owns batch rows [16g,16g+16); colg = bid&63 owns
// H-cols [colg*32, colg*32+32). Wh hi-part (32 cols x 2048 K bf16 = 128KB) in
// LDS for all 512 steps; Wh lo-part in 64 VGPRs/wave. h (hi|lo) ping-pongs in
// global with AGENT-scope (sc1) atomics (cross-XCD coherent).
// Group barrier (64 blocks) = contention-free flag array: each block release-
// stores generation t+1 to its own 256B-strided slot; wave0's 64 lanes poll all
// 64 slots in one vector load per iteration. No same-address RMW serialization.
__global__ __launch_bounds__(512, 2)
void rnn_scan(const u16* __restrict__ WhiT, const u16* __restrict__ WloT,
              const u16* __restrict__ xp, u16* __restrict__ hbuf,
              u16* __restrict__ hidden, unsigned* __restrict__ sync) {
  __shared__ u16 whi[65536];     // 128KB: frag(c2,kt) base (c2*64+kt)*512 u16
  __shared__ float red[3584];    // 14KB: 7 waves x 2 frags x 256 f32

  const int bid = blockIdx.x;
  const int g = bid >> 6;
  const int colg = bid & 63;
  const int rowbase = g * 16;
  const int col0 = colg * 32;
  const int tid = threadIdx.x;
  const int lane = tid & 63;
  const int w = tid >> 6;        // wave = K-slice index, 0..7

  // ---- preload Wh hi into LDS (one-time) ----
  for (int i = tid; i < 8192; i += 512) {
    const int ch = i & 3;
    const int cl = (i >> 2) & 15;
    const int kt = (i >> 6) & 63;
    const int c2 = (i >> 12) & 1;
    bf16x8 v = *(const bf16x8*)(WhiT + (size_t)(col0 + c2 * 16 + cl) * 2048 + kt * 32 + ch * 8);
    *(bf16x8*)&whi[(size_t)(c2 * 64 + kt) * 512 + ch * 128 + cl * 8] = v;
  }
  // ---- preload Wh lo into VGPRs (one-time): wave w covers ktG in [w*8, w*8+8) ----
  bf16x8 wlo[2][8];
  #pragma unroll
  for (int c2 = 0; c2 < 2; ++c2)
    #pragma unroll
    for (int kt = 0; kt < 8; ++kt)
      wlo[c2][kt] = *(const bf16x8*)(WloT + (size_t)(col0 + c2 * 16 + (lane & 15)) * 2048
                                     + (w * 8 + kt) * 32 + (lane >> 4) * 8);
  __syncthreads();

  // flag slots: sync + (g*64 + cb)*64, one u32 per 256B line
  unsigned* myflag = sync + ((size_t)(g * 64 + colg)) * 64;
  unsigned* grpfl  = sync + ((size_t)(g * 64)) * 64;
  bool dead = false;

  const int hrow = rowbase + (lane & 15);

  for (int t = 0; t < Tt; ++t) {
    const u16* hp = hbuf + (size_t)(t & 1) * (64 * 4096);
    u16*       hn = hbuf + (size_t)((t + 1) & 1) * (64 * 4096);

    // ---- batched agent-scope h loads for this wave's K-slice (32 u64, all in flight) ----
    u64 q[8][4];
    const u16* hb = hp + (size_t)hrow * 4096 + (lane >> 4) * 8;
    #pragma unroll
    for (int kt = 0; kt < 8; ++kt) {
      const u16* p = hb + (w * 8 + kt) * 32;
      q[kt][0] = __hip_atomic_load((const u64*)p,          __ATOMIC_RELAXED, __HIP_MEMORY_SCOPE_AGENT);
      q[kt][1] = __hip_atomic_load((const u64*)(p + 4),    __ATOMIC_RELAXED, __HIP_MEMORY_SCOPE_AGENT);
      q[kt][2] = __hip_atomic_load((const u64*)(p + 2048), __ATOMIC_RELAXED, __HIP_MEMORY_SCOPE_AGENT);
      q[kt][3] = __hip_atomic_load((const u64*)(p + 2052), __ATOMIC_RELAXED, __HIP_MEMORY_SCOPE_AGENT);
    }

    f32x4 a0 = (f32x4){0.f, 0.f, 0.f, 0.f};
    f32x4 a1 = (f32x4){0.f, 0.f, 0.f, 0.f};
    #pragma unroll
    for (int kt = 0; kt < 8; ++kt) {
      const int ktG = w * 8 + kt;
      bf16x8 bhi = comb(q[kt][0], q[kt][1]);
      bf16x8 blo = comb(q[kt][2], q[kt][3]);
      bf16x8 w0 = *(const bf16x8*)&whi[(size_t)(0 * 64 + ktG) * 512 + (lane >> 4) * 128 + (lane & 15) * 8];
      bf16x8 w1 = *(const bf16x8*)&whi[(size_t)(1 * 64 + ktG) * 512 + (lane >> 4) * 128 + (lane & 15) * 8];
      a0 = __builtin_amdgcn_mfma_f32_16x16x32_bf16(w0, bhi, a0, 0, 0, 0);
      a0 = __builtin_amdgcn_mfma_f32_16x16x32_bf16(w0, blo, a0, 0, 0, 0);
      a0 = __builtin_amdgcn_mfma_f32_16x16x32_bf16(wlo[0][kt], bhi, a0, 0, 0, 0);
      a1 = __builtin_amdgcn_mfma_f32_16x16x32_bf16(w1, bhi, a1, 0, 0, 0);
      a1 = __builtin_amdgcn_mfma_f32_16x16x32_bf16(w1, blo, a1, 0, 0, 0);
      a1 = __builtin_amdgcn_mfma_f32_16x16x32_bf16(wlo[1][kt], bhi, a1, 0, 0, 0);
    }

    // ---- K-reduce across waves ----
    if (w != 0) {
      *(f32x4*)&red[((w - 1) * 2 + 0) * 256 + lane * 4] = a0;
      *(f32x4*)&red[((w - 1) * 2 + 1) * 256 + lane * 4] = a1;
    }
    __syncthreads();
    if (w == 0) {
      #pragma unroll
      for (int j = 0; j < 7; ++j) {
        a0 += *(const f32x4*)&red[(j * 2 + 0) * 256 + lane * 4];
        a1 += *(const f32x4*)&red[(j * 2 + 1) * 256 + lane * 4];
      }
      // D: batch row = lane&15 (hrow); wh_col_local = c*16 + (lane>>4)*4 + q
      const int cl0 = (lane >> 4) * 4;
      const u16* xq = xp + ((size_t)t * Bb + hrow) * 2048 + col0;
      ushort4 x0 = *(const ushort4*)(xq + cl0);
      ushort4 x1 = *(const ushort4*)(xq + 16 + cl0);
      u16 h0_[4], l0_[4], h1_[4], l1_[4];
      #pragma unroll
      for (int qq = 0; qq < 4; ++qq) {
        float v0 = tanhf(a0[qq] + b2f(((const u16*)&x0)[qq]));
        float v1 = tanhf(a1[qq] + b2f(((const u16*)&x1)[qq]));
        h0_[qq] = f2b(v0); l0_[qq] = f2b(v0 - b2f(h0_[qq]));
        h1_[qq] = f2b(v1); l1_[qq] = f2b(v1 - b2f(h1_[qq]));
      }
      u64 ph0 = pack4(h0_[0], h0_[1], h0_[2], h0_[3]);
      u64 pl0 = pack4(l0_[0], l0_[1], l0_[2], l0_[3]);
      u64 ph1 = pack4(h1_[0], h1_[1], h1_[2], h1_[3]);
      u64 pl1 = pack4(l1_[0], l1_[1], l1_[2], l1_[3]);
      u16* hd = hn + (size_t)hrow * 4096 + col0 + cl0;
      __hip_atomic_store((u64*)hd,            ph0, __ATOMIC_RELAXED, __HIP_MEMORY_SCOPE_AGENT);
      __hip_atomic_store((u64*)(hd + 16),     ph1, __ATOMIC_RELAXED, __HIP_MEMORY_SCOPE_AGENT);
      __hip_atomic_store((u64*)(hd + 2048),   pl0, __ATOMIC_RELAXED, __HIP_MEMORY_SCOPE_AGENT);
      __hip_atomic_store((u64*)(hd + 2064),   pl1, __ATOMIC_RELAXED, __HIP_MEMORY_SCOPE_AGENT);
      u64* hv = (u64*)(hidden + ((size_t)hrow * Tt + t) * Hh + col0 + cl0);
      hv[0] = ph0;
      *(u64*)((u16*)hv + 16) = ph1;
    }

    // ---- group barrier: arrive (own flag, release) + poll 64 flags in parallel ----
    __syncthreads();                    // all block writes issued & drained (vmcnt0)
    if (tid == 0) {
      __threadfence();                  // publish agent-scope h stores
      __hip_atomic_store(myflag, (unsigned)(t + 1), __ATOMIC_RELEASE, __HIP_MEMORY_SCOPE_AGENT);
    }
    if (tid < 64 && !dead) {
      unsigned* fp = grpfl + tid * 64;
      unsigned polls = 0;
      while (__hip_atomic_load(fp, __ATOMIC_RELAXED, __HIP_MEMORY_SCOPE_AGENT) < (unsigned)(t + 1)) {
        if (++polls > 2000000u) { dead = true; break; }   // anti-hang escape
      }
      (void)__hip_atomic_load(fp, __ATOMIC_ACQUIRE, __HIP_MEMORY_SCOPE_AGENT);
    }
    __syncthreads();
  }
}

// ---------------- loss ----------------

__global__ __launch_bounds__(256)
void row_nll(const float* __restrict__ logits, const int* __restrict__ tgt,
             float* __restrict__ nll) {
  const int m = blockIdx.x;
  const float4* rp = (const float4*)(logits + (size_t)m * Vv);
  const int tid = threadIdx.x;
  float4 v[8];
  float mx = -1e30f;
  #pragma unroll
  for (int j = 0; j < 8; ++j) {
    v[j] = rp[tid + j * 256];
    mx = fmaxf(mx, fmaxf(fmaxf(v[j].x, v[j].y), fmaxf(v[j].z, v[j].w)));
  }
  mx = wave_max(mx);
  __shared__ float sm[4], ss[4];
  const int w = tid >> 6;
  if ((tid & 63) == 0) sm[w] = mx;
  __syncthreads();
  mx = fmaxf(fmaxf(sm[0], sm[1]), fmaxf(sm[2], sm[3]));
  float s = 0.f;
  #pragma unroll
  for (int j = 0; j < 8; ++j)
    s += expf(v[j].x - mx) + expf(v[j].y - mx) + expf(v[j].z - mx) + expf(v[j].w - mx);
  s = wave_sum(s);
  if ((tid & 63) == 0) ss[w] = s;
  __syncthreads();
  if (tid == 0) {
    float S = ss[0] + ss[1] + ss[2] + ss[3];
    int tg = tgt[m];
    float o = 0.f;
    if (tg != -1) {
      float lt = logits[(size_t)m * Vv + tg];
      o = mx + logf(S) - lt;
    }
    nll[m] = o;
  }
}

__global__ __launch_bounds__(256)
void loss_reduce(const float* __restrict__ nll, const int* __restrict__ tgt,
                 float* __restrict__ out) {
  const int tid = threadIdx.x;
  float s = 0.f, c = 0.f;
  for (int i = tid; i < Bb * Tt; i += 256) {
    s += nll[i];
    c += (tgt[i] != -1) ? 1.f : 0.f;
  }
  s = wave_sum(s);
  c = wave_sum(c);
  __shared__ float as_[4], ac_[4];
  const int w = tid >> 6;
  if ((tid & 63) == 0) { as_[w] = s; ac_[w] = c; }
  __syncthreads();
  if (tid == 0) {
    float S = as_[0] + as_[1] + as_[2] + as_[3];
    float C = ac_[0] + ac_[1] + ac_[2] + ac_[3];
    out[0] = S / fmaxf(C, 1.f);
  }
}

// ---------------- launch ----------------

extern "C" void kernel_launch(void* const* d_in, const int* in_sizes, int n_in,
                              void* d_out, int out_size, void* d_ws, size_t ws_size,
                              hipStream_t stream) {
  const int*   idx    = (const int*)d_in[0];
  const int*   tgt    = (const int*)d_in[1];
  const float* W_E    = (const float*)d_in[2];
  const float* start  = (const float*)d_in[3];
  const float* W_xh   = (const float*)d_in[4];
  const float* b_xh   = (const float*)d_in[5];
  const float* W_head = (const float*)d_in[6];
  const float* b_head = (const float*)d_in[7];

  // workspace layout (~314 MB). emb2 (dead after GEMM1) aliases hidden.
  char* ws = (char*)d_ws;
  u16*      emb2   = (u16*)(ws);                                  // 32768x2048 bf16 = 128MB
  u16*      hidden = (u16*)(ws);                                  // 32768x2048 bf16 (alias)
  u16*      xproj  = (u16*)(ws + (size_t)128 * 1024 * 1024);      // [T][B][H] bf16 = 128MB
  u16*      WheadT = (u16*)(ws + (size_t)256 * 1024 * 1024);      // 8192x2048 bf16 = 32MB
  u16*      WhiT   = (u16*)(ws + (size_t)288 * 1024 * 1024);      // 2048x2048 bf16 = 8MB
  u16*      WloT   = (u16*)(ws + (size_t)296 * 1024 * 1024);      // 2048x2048 bf16 = 8MB
  u16*      WxT2   = (u16*)(ws + (size_t)304 * 1024 * 1024);      // 2048x2048 bf16 = 8MB
  u16*      hbuf   = (u16*)(ws + (size_t)312 * 1024 * 1024);      // 2x64x4096 bf16 = 1MB
  float*    nll    = (float*)(ws + (size_t)313 * 1024 * 1024);    // 32768 f32 = 128KB
  unsigned* sync   = (unsigned*)(ws + (size_t)313 * 1024 * 1024 + 128 * 1024); // 64KB flags

  embed_cast<<<Bb * Tt, 256, 0, stream>>>(W_E, idx, emb2);
  transpose_cast<<<dim3(Hh / 32, Ee / 32), 256, 0, stream>>>(W_xh, WxT2, Ee, Hh, 1);
  transpose_cast_hilo<<<dim3(Hh / 32, Hh / 32), 256, 0, stream>>>(W_xh + (size_t)Ee * Hh, WhiT, WloT, Hh, Hh);
  transpose_cast<<<dim3(Vv / 32, Hh / 32), 256, 0, stream>>>(W_head, WheadT, Hh, Vv, 0);
  h0_init<<<Bb, 256, 0, stream>>>(start, hbuf);
  hipMemsetAsync(sync, 0, 65536, stream);

  // xproj = [emb_hi|emb_lo] @ [Wx;Wx] + b_xh   (K=2048 effective)
  gemm_bt<1><<<dim3(256, 16), 256, 0, stream>>>(emb2, WxT2, b_xh, xproj, Bb * Tt, Hh, 2048);

  // persistent scan: 256 blocks (1/CU), 512 threads, Wh resident in LDS+VGPR
  rnn_scan<<<256, 512, 0, stream>>>(WhiT, WloT, xproj, hbuf, hidden, sync);

  // logits = hidden @ W_head + b_head  -> d_out
  gemm_bt<0><<<dim3(256, 64), 256, 0, stream>>>(hidden, WheadT, b_head, d_out, Bb * Tt, Vv, 2048);

  row_nll<<<Bb * Tt, 256, 0, stream>>>((const float*)d_out, tgt, nll);
  loss_reduce<<<1, 256, 0, stream>>>(nll, tgt, (float*)d_out + ((size_t)out_size - 1));
}

// Round 4
// 10285.181 us; speedup vs baseline: 1.3052x; 1.3052x over previous
//
#include <hip/hip_runtime.h>
#include <hip/hip_bf16.h>
#include <math.h>
#include <stdint.h>

// RNN LM forward: B=64 T=512 V=8192 E=1024 H=2048
// out = [logits (B*T*V f32) | loss (1 f32)]
#define Bb 64
#define Tt 512
#define Vv 8192
#define Ee 1024
#define Hh 2048

typedef unsigned short u16;
typedef unsigned long long u64;
typedef __attribute__((ext_vector_type(8))) short bf16x8;   // 8 bf16 = 4 VGPR (MFMA A/B frag)
typedef __attribute__((ext_vector_type(4))) float f32x4;    // MFMA C/D frag

__device__ __forceinline__ u16 f2b(float f) {               // f32 -> bf16 RNE
  unsigned u = __float_as_uint(f);
  u += 0x7FFF + ((u >> 16) & 1);
  return (u16)(u >> 16);
}
__device__ __forceinline__ float b2f(u16 h) {
  return __uint_as_float(((unsigned)h) << 16);
}
__device__ __forceinline__ u64 pack4(u16 a, u16 b, u16 c, u16 d) {
  return (u64)a | ((u64)b << 16) | ((u64)c << 32) | ((u64)d << 48);
}

// pipelined agent-coherent 16B load: issue-only (no waitcnt) — caller must
// s_waitcnt vmcnt(0) + sched_barrier before consuming. sc1 = agent scope
// (same flag hipcc emits for __hip_atomic_load AGENT; bypasses stale XCD-L2).
__device__ __forceinline__ void gload16_sc1(bf16x8& dst, const void* addr) {
  asm volatile("global_load_dwordx4 %0, %1, off sc1"
               : "=v"(dst) : "v"(addr) : "memory");
}

__device__ __forceinline__ void gll16(const u16* g, u16* l) {
  __builtin_amdgcn_global_load_lds((__attribute__((address_space(1))) void*)g,
                                   (__attribute__((address_space(3))) void*)l, 16, 0, 0);
}

__device__ __forceinline__ float wave_max(float v) {
  #pragma unroll
  for (int d = 32; d; d >>= 1) v = fmaxf(v, __shfl_xor(v, d, 64));
  return v;
}
__device__ __forceinline__ float wave_sum(float v) {
  #pragma unroll
  for (int d = 32; d; d >>= 1) v += __shfl_xor(v, d, 64);
  return v;
}

// ---------------- prep kernels ----------------

// gather W_E rows by idx, split into bf16 hi|lo halves along K: emb2[m] = [hi(1024) | lo(1024)]
__global__ __launch_bounds__(256)
void embed_cast(const float* __restrict__ WE, const int* __restrict__ idx,
                u16* __restrict__ emb2) {
  const int m = blockIdx.x;
  const int row = idx[m];
  const float4 v = ((const float4*)(WE + (size_t)row * Ee))[threadIdx.x];
  ushort4 hi, lo;
  hi.x = f2b(v.x); lo.x = f2b(v.x - b2f(hi.x));
  hi.y = f2b(v.y); lo.y = f2b(v.y - b2f(hi.y));
  hi.z = f2b(v.z); lo.z = f2b(v.z - b2f(hi.z));
  hi.w = f2b(v.w); lo.w = f2b(v.w - b2f(hi.w));
  u16* d = emb2 + (size_t)m * 2048;
  ((ushort4*)d)[threadIdx.x] = hi;
  ((ushort4*)(d + Ee))[threadIdx.x] = lo;
}

// src[R][C] f32 -> dst[C][R<<dup] bf16 (transpose+cast hi); if dup, duplicate: [v | v]
__global__ __launch_bounds__(256)
void transpose_cast(const float* __restrict__ src, u16* __restrict__ dst,
                    int R, int C, int dup) {
  __shared__ float tile[32][33];
  const int bi = blockIdx.x;  // along C
  const int bj = blockIdx.y;  // along R
  const int tid = threadIdx.x;
  const int r  = tid >> 3;
  const int c4 = (tid & 7) * 4;
  float4 v = *(const float4*)(src + (size_t)(bj * 32 + r) * C + bi * 32 + c4);
  tile[r][c4 + 0] = v.x; tile[r][c4 + 1] = v.y;
  tile[r][c4 + 2] = v.z; tile[r][c4 + 3] = v.w;
  __syncthreads();
  const int RL = R << dup;
  ushort4 o;
  o.x = f2b(tile[c4 + 0][r]); o.y = f2b(tile[c4 + 1][r]);
  o.z = f2b(tile[c4 + 2][r]); o.w = f2b(tile[c4 + 3][r]);
  u16* d = dst + (size_t)(bi * 32 + r) * RL + bj * 32 + c4;
  *(ushort4*)d = o;
  if (dup) *(ushort4*)(d + R) = o;
}

// src[R][C] f32 -> hi[C][R], lo[C][R] bf16 (transpose + hi/lo split)
__global__ __launch_bounds__(256)
void transpose_cast_hilo(const float* __restrict__ src, u16* __restrict__ dhi,
                         u16* __restrict__ dlo, int R, int C) {
  __shared__ float tile[32][33];
  const int bi = blockIdx.x;  // along C
  const int bj = blockIdx.y;  // along R
  const int tid = threadIdx.x;
  const int r  = tid >> 3;
  const int c4 = (tid & 7) * 4;
  float4 v = *(const float4*)(src + (size_t)(bj * 32 + r) * C + bi * 32 + c4);
  tile[r][c4 + 0] = v.x; tile[r][c4 + 1] = v.y;
  tile[r][c4 + 2] = v.z; tile[r][c4 + 3] = v.w;
  __syncthreads();
  ushort4 oh, ol;
  #pragma unroll
  for (int j = 0; j < 4; ++j) {
    float x = tile[c4 + j][r];
    u16 h = f2b(x);
    ((u16*)&oh)[j] = h;
    ((u16*)&ol)[j] = f2b(x - b2f(h));
  }
  size_t off = (size_t)(bi * 32 + r) * R + bj * 32 + c4;
  *(ushort4*)(dhi + off) = oh;
  *(ushort4*)(dlo + off) = ol;
}

// h0[b] = [hi(start) | lo(start)] per batch row
__global__ __launch_bounds__(256)
void h0_init(const float* __restrict__ start, u16* __restrict__ hbuf) {
  const int b = blockIdx.x;
  #pragma unroll
  for (int j = 0; j < 8; ++j) {
    int n = threadIdx.x * 8 + j;
    float x = start[n];
    u16 hi = f2b(x);
    u16 lo = f2b(x - b2f(hi));
    hbuf[(size_t)b * 4096 + n] = hi;
    hbuf[(size_t)b * 4096 + 2048 + n] = lo;
  }
}

// ---------------- GEMM (m97-style 128x128 tile, BK=32, 4 waves) ----------------
// C[M x N] = A[M x K] * Bt[N x K]^T, bf16 inputs, f32 accum.
// MODE 0: out f32 at [row*N+col] + bias   (head GEMM -> logits in d_out)
// MODE 1: out bf16 at [(t*B+b)*N+col] + bias, row = b*T+t  (xproj, t-major)
// XCD-aware block swizzle (T1): nwg % 8 == 0 for both call sites.
template <int MODE>
__global__ __launch_bounds__(256, 2)
void gemm_bt(const u16* __restrict__ A, const u16* __restrict__ Bt,
             const float* __restrict__ bias, void* __restrict__ outp,
             int M, int N, int K) {
  __shared__ u16 ldsA[128 * 32];
  __shared__ u16 ldsB[128 * 32];
  const int tid = threadIdx.x;
  const int lane = tid & 63;
  const int w = tid >> 6;
  const int wr = w >> 1, wc = w & 1;

  const int nwg = gridDim.x * gridDim.y;
  const int lin = blockIdx.y * gridDim.x + blockIdx.x;
  const int swz = (lin & 7) * (nwg >> 3) + (lin >> 3);
  const int bm = swz % gridDim.x;
  const int bn = swz / gridDim.x;

  const int srow = w * 32 + (lane >> 2);
  const int scol = (lane & 3) * 8;
  const u16* a0 = A + (size_t)(bm * 128 + srow) * K + scol;
  const u16* b0 = Bt + (size_t)(bn * 128 + srow) * K + scol;
  u16* lA0 = ldsA + w * 1024;
  u16* lA1 = ldsA + w * 1024 + 512;
  u16* lB0 = ldsB + w * 1024;
  u16* lB1 = ldsB + w * 1024 + 512;

  f32x4 acc[4][4];
  #pragma unroll
  for (int m = 0; m < 4; ++m)
    #pragma unroll
    for (int n = 0; n < 4; ++n)
      acc[m][n] = (f32x4){0.f, 0.f, 0.f, 0.f};

  const int nk = K >> 5;
  for (int kt = 0; kt < nk; ++kt) {
    __syncthreads();
    const u16* ak = a0 + kt * 32;
    const u16* bk = b0 + kt * 32;
    gll16(ak, lA0);
    gll16(ak + 16 * (size_t)K, lA1);
    gll16(bk, lB0);
    gll16(bk + 16 * (size_t)K, lB1);
    __syncthreads();
    bf16x8 af[4], bfr[4];
    #pragma unroll
    for (int i = 0; i < 4; ++i) {
      af[i]  = *(const bf16x8*)&ldsA[(wr * 64 + i * 16 + (lane & 15)) * 32 + (lane >> 4) * 8];
      bfr[i] = *(const bf16x8*)&ldsB[(wc * 64 + i * 16 + (lane & 15)) * 32 + (lane >> 4) * 8];
    }
    #pragma unroll
    for (int m = 0; m < 4; ++m)
      #pragma unroll
      for (int n = 0; n < 4; ++n)
        acc[m][n] = __builtin_amdgcn_mfma_f32_16x16x32_bf16(af[m], bfr[n], acc[m][n], 0, 0, 0);
  }

  const int r0 = bm * 128 + wr * 64 + (lane >> 4) * 4;
  const int c0 = bn * 128 + wc * 64 + (lane & 15);
  #pragma unroll
  for (int n = 0; n < 4; ++n) {
    const int col = c0 + n * 16;
    const float bv = bias[col];
    #pragma unroll
    for (int m = 0; m < 4; ++m) {
      #pragma unroll
      for (int q = 0; q < 4; ++q) {
        const int row = r0 + m * 16 + q;
        float v = acc[m][n][q] + bv;
        if (MODE == 0) {
          ((float*)outp)[(size_t)row * N + col] = v;
        } else {
          const int b = row >> 9, t = row & 511;   // row = b*T + t
          ((u16*)outp)[((size_t)t * Bb + b) * N + col] = f2b(v);
        }
      }
    }
  }
}

// ---------------- persistent recurrence scan ----------------
// 256 blocks x 512 thr (8 waves), 1 block/CU (145KB LDS).
// Block bid: group g = bid>>6 owns batch rows [16g,16g+16); colg = bid&63 owns
// H-cols [colg*32, colg*32+32). Wh hi-part (32 cols x 2048 K bf16 = 128KB) in
// LDS for all 512 steps; Wh lo-part in 64 VGPRs/wave. h (hi|lo) ping-pongs in
// global. h loads: inline-asm global_load_dwordx4 sc1 issued back-to-back
// (16 in flight), single s_waitcnt vmcnt(0) -- r2/r3's per-atomic-load
// serialization (32 x ~550ns = 17.6us/step) was the whole kernel cost.
// Group barrier (64 blocks) = r2's counter design (A/B-measured best).
__global__ __launch_bounds__(512, 2)
void rnn_scan(const u16* __restrict__ WhiT, const u16* __restrict__ WloT,
              const u16* __restrict__ xp, u16* __restrict__ hbuf,
              u16* __restrict__ hidden, unsigned* __restrict__ sync) {
  __shared__ u16 whi[65536];     // 128KB: frag(c2,kt) base (c2*64+kt)*512 u16
  __shared__ float red[3584];    // 14KB: 7 waves x 2 frags x 256 f32

  const int bid = blockIdx.x;
  const int g = bid >> 6;
  const int colg = bid & 63;
  const int rowbase = g * 16;
  const int col0 = colg * 32;
  const int tid = threadIdx.x;
  const int lane = tid & 63;
  const int w = tid >> 6;        // wave = K-slice index, 0..7

  // ---- preload Wh hi into LDS (one-time) ----
  for (int i = tid; i < 8192; i += 512) {
    const int ch = i & 3;
    const int cl = (i >> 2) & 15;
    const int kt = (i >> 6) & 63;
    const int c2 = (i >> 12) & 1;
    bf16x8 v = *(const bf16x8*)(WhiT + (size_t)(col0 + c2 * 16 + cl) * 2048 + kt * 32 + ch * 8);
    *(bf16x8*)&whi[(size_t)(c2 * 64 + kt) * 512 + ch * 128 + cl * 8] = v;
  }
  // ---- preload Wh lo into VGPRs (one-time): wave w covers ktG in [w*8, w*8+8) ----
  bf16x8 wlo[2][8];
  #pragma unroll
  for (int c2 = 0; c2 < 2; ++c2)
    #pragma unroll
    for (int kt = 0; kt < 8; ++kt)
      wlo[c2][kt] = *(const bf16x8*)(WloT + (size_t)(col0 + c2 * 16 + (lane & 15)) * 2048
                                     + (w * 8 + kt) * 32 + (lane >> 4) * 8);
  __syncthreads();

  unsigned* cnt = sync + g * 64;
  unsigned* gn  = sync + g * 64 + 32;
  bool dead = false;

  const int hrow = rowbase + (lane & 15);

  for (int t = 0; t < Tt; ++t) {
    const u16* hp = hbuf + (size_t)(t & 1) * (64 * 4096);
    u16*       hn = hbuf + (size_t)((t + 1) & 1) * (64 * 4096);

    // ---- batched h loads for this wave's K-slice: 16 x 16B, all in flight ----
    bf16x8 qh[8], ql[8];
    const u16* hb = hp + (size_t)hrow * 4096 + (lane >> 4) * 8;
    #pragma unroll
    for (int kt = 0; kt < 8; ++kt) {
      const u16* ph = hb + (w * 8 + kt) * 32;
      gload16_sc1(qh[kt], ph);           // hi half
      gload16_sc1(ql[kt], ph + 2048);    // lo half
    }
    asm volatile("s_waitcnt vmcnt(0)" ::: "memory");
    __builtin_amdgcn_sched_barrier(0);   // rule #18: pin MFMAs below the waitcnt

    f32x4 a0 = (f32x4){0.f, 0.f, 0.f, 0.f};
    f32x4 a1 = (f32x4){0.f, 0.f, 0.f, 0.f};
    #pragma unroll
    for (int kt = 0; kt < 8; ++kt) {
      const int ktG = w * 8 + kt;
      bf16x8 w0 = *(const bf16x8*)&whi[(size_t)(0 * 64 + ktG) * 512 + (lane >> 4) * 128 + (lane & 15) * 8];
      bf16x8 w1 = *(const bf16x8*)&whi[(size_t)(1 * 64 + ktG) * 512 + (lane >> 4) * 128 + (lane & 15) * 8];
      a0 = __builtin_amdgcn_mfma_f32_16x16x32_bf16(w0, qh[kt], a0, 0, 0, 0);
      a0 = __builtin_amdgcn_mfma_f32_16x16x32_bf16(w0, ql[kt], a0, 0, 0, 0);
      a0 = __builtin_amdgcn_mfma_f32_16x16x32_bf16(wlo[0][kt], qh[kt], a0, 0, 0, 0);
      a1 = __builtin_amdgcn_mfma_f32_16x16x32_bf16(w1, qh[kt], a1, 0, 0, 0);
      a1 = __builtin_amdgcn_mfma_f32_16x16x32_bf16(w1, ql[kt], a1, 0, 0, 0);
      a1 = __builtin_amdgcn_mfma_f32_16x16x32_bf16(wlo[1][kt], qh[kt], a1, 0, 0, 0);
    }

    // ---- K-reduce across waves ----
    if (w != 0) {
      *(f32x4*)&red[((w - 1) * 2 + 0) * 256 + lane * 4] = a0;
      *(f32x4*)&red[((w - 1) * 2 + 1) * 256 + lane * 4] = a1;
    }
    __syncthreads();
    if (w == 0) {
      #pragma unroll
      for (int j = 0; j < 7; ++j) {
        a0 += *(const f32x4*)&red[(j * 2 + 0) * 256 + lane * 4];
        a1 += *(const f32x4*)&red[(j * 2 + 1) * 256 + lane * 4];
      }
      // D: batch row = lane&15 (hrow); wh_col_local = c*16 + (lane>>4)*4 + q
      const int cl0 = (lane >> 4) * 4;
      const u16* xq = xp + ((size_t)t * Bb + hrow) * 2048 + col0;
      ushort4 x0 = *(const ushort4*)(xq + cl0);
      ushort4 x1 = *(const ushort4*)(xq + 16 + cl0);
      u16 h0_[4], l0_[4], h1_[4], l1_[4];
      #pragma unroll
      for (int qq = 0; qq < 4; ++qq) {
        float v0 = tanhf(a0[qq] + b2f(((const u16*)&x0)[qq]));
        float v1 = tanhf(a1[qq] + b2f(((const u16*)&x1)[qq]));
        h0_[qq] = f2b(v0); l0_[qq] = f2b(v0 - b2f(h0_[qq]));
        h1_[qq] = f2b(v1); l1_[qq] = f2b(v1 - b2f(h1_[qq]));
      }
      u64 ph0 = pack4(h0_[0], h0_[1], h0_[2], h0_[3]);
      u64 pl0 = pack4(l0_[0], l0_[1], l0_[2], l0_[3]);
      u64 ph1 = pack4(h1_[0], h1_[1], h1_[2], h1_[3]);
      u64 pl1 = pack4(l1_[0], l1_[1], l1_[2], l1_[3]);
      u16* hd = hn + (size_t)hrow * 4096 + col0 + cl0;
      __hip_atomic_store((u64*)hd,            ph0, __ATOMIC_RELAXED, __HIP_MEMORY_SCOPE_AGENT);
      __hip_atomic_store((u64*)(hd + 16),     ph1, __ATOMIC_RELAXED, __HIP_MEMORY_SCOPE_AGENT);
      __hip_atomic_store((u64*)(hd + 2048),   pl0, __ATOMIC_RELAXED, __HIP_MEMORY_SCOPE_AGENT);
      __hip_atomic_store((u64*)(hd + 2064),   pl1, __ATOMIC_RELAXED, __HIP_MEMORY_SCOPE_AGENT);
      u64* hv = (u64*)(hidden + ((size_t)hrow * Tt + t) * Hh + col0 + cl0);
      hv[0] = ph0;
      *(u64*)((u16*)hv + 16) = ph1;
    }

    // ---- group barrier (64 blocks): counter + generation (r2 design) ----
    __syncthreads();                    // drains vmcnt -> h stores complete
    if (tid == 0) {
      if (__hip_atomic_fetch_add(cnt, 1u, __ATOMIC_ACQ_REL, __HIP_MEMORY_SCOPE_AGENT) == 63u) {
        __hip_atomic_store(cnt, 0u, __ATOMIC_RELAXED, __HIP_MEMORY_SCOPE_AGENT);
        __hip_atomic_store(gn, (unsigned)(t + 1), __ATOMIC_RELEASE, __HIP_MEMORY_SCOPE_AGENT);
      } else if (!dead) {
        unsigned polls = 0;
        while (__hip_atomic_load(gn, __ATOMIC_RELAXED, __HIP_MEMORY_SCOPE_AGENT) < (unsigned)(t + 1)) {
          if (++polls > 4000000u) { dead = true; break; }   // anti-hang escape
        }
        (void)__hip_atomic_load(gn, __ATOMIC_ACQUIRE, __HIP_MEMORY_SCOPE_AGENT);
      }
    }
    __syncthreads();
  }
}

// ---------------- loss ----------------

__global__ __launch_bounds__(256)
void row_nll(const float* __restrict__ logits, const int* __restrict__ tgt,
             float* __restrict__ nll) {
  const int m = blockIdx.x;
  const float4* rp = (const float4*)(logits + (size_t)m * Vv);
  const int tid = threadIdx.x;
  float4 v[8];
  float mx = -1e30f;
  #pragma unroll
  for (int j = 0; j < 8; ++j) {
    v[j] = rp[tid + j * 256];
    mx = fmaxf(mx, fmaxf(fmaxf(v[j].x, v[j].y), fmaxf(v[j].z, v[j].w)));
  }
  mx = wave_max(mx);
  __shared__ float sm[4], ss[4];
  const int w = tid >> 6;
  if ((tid & 63) == 0) sm[w] = mx;
  __syncthreads();
  mx = fmaxf(fmaxf(sm[0], sm[1]), fmaxf(sm[2], sm[3]));
  float s = 0.f;
  #pragma unroll
  for (int j = 0; j < 8; ++j)
    s += expf(v[j].x - mx) + expf(v[j].y - mx) + expf(v[j].z - mx) + expf(v[j].w - mx);
  s = wave_sum(s);
  if ((tid & 63) == 0) ss[w] = s;
  __syncthreads();
  if (tid == 0) {
    float S = ss[0] + ss[1] + ss[2] + ss[3];
    int tg = tgt[m];
    float o = 0.f;
    if (tg != -1) {
      float lt = logits[(size_t)m * Vv + tg];
      o = mx + logf(S) - lt;
    }
    nll[m] = o;
  }
}

__global__ __launch_bounds__(256)
void loss_reduce(const float* __restrict__ nll, const int* __restrict__ tgt,
                 float* __restrict__ out) {
  const int tid = threadIdx.x;
  float s = 0.f, c = 0.f;
  for (int i = tid; i < Bb * Tt; i += 256) {
    s += nll[i];
    c += (tgt[i] != -1) ? 1.f : 0.f;
  }
  s = wave_sum(s);
  c = wave_sum(c);
  __shared__ float as_[4], ac_[4];
  const int w = tid >> 6;
  if ((tid & 63) == 0) { as_[w] = s; ac_[w] = c; }
  __syncthreads();
  if (tid == 0) {
    float S = as_[0] + as_[1] + as_[2] + as_[3];
    float C = ac_[0] + ac_[1] + ac_[2] + ac_[3];
    out[0] = S / fmaxf(C, 1.f);
  }
}

// ---------------- launch ----------------

extern "C" void kernel_launch(void* const* d_in, const int* in_sizes, int n_in,
                              void* d_out, int out_size, void* d_ws, size_t ws_size,
                              hipStream_t stream) {
  const int*   idx    = (const int*)d_in[0];
  const int*   tgt    = (const int*)d_in[1];
  const float* W_E    = (const float*)d_in[2];
  const float* start  = (const float*)d_in[3];
  const float* W_xh   = (const float*)d_in[4];
  const float* b_xh   = (const float*)d_in[5];
  const float* W_head = (const float*)d_in[6];
  const float* b_head = (const float*)d_in[7];

  // workspace layout (~314 MB). emb2 (dead after GEMM1) aliases hidden.
  char* ws = (char*)d_ws;
  u16*      emb2   = (u16*)(ws);                                  // 32768x2048 bf16 = 128MB
  u16*      hidden = (u16*)(ws);                                  // 32768x2048 bf16 (alias)
  u16*      xproj  = (u16*)(ws + (size_t)128 * 1024 * 1024);      // [T][B][H] bf16 = 128MB
  u16*      WheadT = (u16*)(ws + (size_t)256 * 1024 * 1024);      // 8192x2048 bf16 = 32MB
  u16*      WhiT   = (u16*)(ws + (size_t)288 * 1024 * 1024);      // 2048x2048 bf16 = 8MB
  u16*      WloT   = (u16*)(ws + (size_t)296 * 1024 * 1024);      // 2048x2048 bf16 = 8MB
  u16*      WxT2   = (u16*)(ws + (size_t)304 * 1024 * 1024);      // 2048x2048 bf16 = 8MB
  u16*      hbuf   = (u16*)(ws + (size_t)312 * 1024 * 1024);      // 2x64x4096 bf16 = 1MB
  float*    nll    = (float*)(ws + (size_t)313 * 1024 * 1024);    // 32768 f32 = 128KB
  unsigned* sync   = (unsigned*)(ws + (size_t)313 * 1024 * 1024 + 128 * 1024); // 1KB

  embed_cast<<<Bb * Tt, 256, 0, stream>>>(W_E, idx, emb2);
  transpose_cast<<<dim3(Hh / 32, Ee / 32), 256, 0, stream>>>(W_xh, WxT2, Ee, Hh, 1);
  transpose_cast_hilo<<<dim3(Hh / 32, Hh / 32), 256, 0, stream>>>(W_xh + (size_t)Ee * Hh, WhiT, WloT, Hh, Hh);
  transpose_cast<<<dim3(Vv / 32, Hh / 32), 256, 0, stream>>>(W_head, WheadT, Hh, Vv, 0);
  h0_init<<<Bb, 256, 0, stream>>>(start, hbuf);
  hipMemsetAsync(sync, 0, 1024, stream);

  // xproj = [emb_hi|emb_lo] @ [Wx;Wx] + b_xh   (K=2048 effective)
  gemm_bt<1><<<dim3(256, 16), 256, 0, stream>>>(emb2, WxT2, b_xh, xproj, Bb * Tt, Hh, 2048);

  // persistent scan: 256 blocks (1/CU), 512 threads, Wh resident in LDS+VGPR
  rnn_scan<<<256, 512, 0, stream>>>(WhiT, WloT, xproj, hbuf, hidden, sync);

  // logits = hidden @ W_head + b_head  -> d_out
  gemm_bt<0><<<dim3(256, 64), 256, 0, stream>>>(hidden, WheadT, b_head, d_out, Bb * Tt, Vv, 2048);

  row_nll<<<Bb * Tt, 256, 0, stream>>>((const float*)d_out, tgt, nll);
  loss_reduce<<<1, 256, 0, stream>>>(nll, tgt, (float*)d_out + ((size_t)out_size - 1));
}

// Round 5
// 5669.943 us; speedup vs baseline: 2.3675x; 1.8140x over previous
//
#include <hip/hip_runtime.h>
#include <hip/hip_bf16.h>
#include <math.h>
#include <stdint.h>

// RNN LM forward: B=64 T=512 V=8192 E=1024 H=2048
// out = [logits (B*T*V f32) | loss (1 f32)]
#define Bb 64
#define Tt 512
#define Vv 8192
#define Ee 1024
#define Hh 2048

typedef unsigned short u16;
typedef unsigned long long u64;
typedef __attribute__((ext_vector_type(8))) short bf16x8;   // 8 bf16 = 4 VGPR (MFMA A/B frag)
typedef __attribute__((ext_vector_type(4))) float f32x4;    // MFMA C/D frag

__device__ __forceinline__ u16 f2b(float f) {               // f32 -> bf16 RNE
  unsigned u = __float_as_uint(f);
  u += 0x7FFF + ((u >> 16) & 1);
  return (u16)(u >> 16);
}
__device__ __forceinline__ float b2f(u16 h) {
  return __uint_as_float(((unsigned)h) << 16);
}
__device__ __forceinline__ u64 pack4(u16 a, u16 b, u16 c, u16 d) {
  return (u64)a | ((u64)b << 16) | ((u64)c << 32) | ((u64)d << 48);
}

// pipelined agent-coherent 16B load: issue-only (no waitcnt) — caller must
// s_waitcnt vmcnt(0) + sched_barrier before consuming. sc1 = agent scope,
// bypasses XCD-private L2 (reads the L3 coherence point directly).
__device__ __forceinline__ void gload16_sc1(bf16x8& dst, const void* addr) {
  asm volatile("global_load_dwordx4 %0, %1, off sc1"
               : "=v"(dst) : "v"(addr) : "memory");
}

__device__ __forceinline__ void gll16(const u16* g, u16* l) {
  __builtin_amdgcn_global_load_lds((__attribute__((address_space(1))) void*)g,
                                   (__attribute__((address_space(3))) void*)l, 16, 0, 0);
}

__device__ __forceinline__ float wave_max(float v) {
  #pragma unroll
  for (int d = 32; d; d >>= 1) v = fmaxf(v, __shfl_xor(v, d, 64));
  return v;
}
__device__ __forceinline__ float wave_sum(float v) {
  #pragma unroll
  for (int d = 32; d; d >>= 1) v += __shfl_xor(v, d, 64);
  return v;
}

// ---------------- prep kernels ----------------

// gather W_E rows by idx, split into bf16 hi|lo halves along K: emb2[m] = [hi(1024) | lo(1024)]
__global__ __launch_bounds__(256)
void embed_cast(const float* __restrict__ WE, const int* __restrict__ idx,
                u16* __restrict__ emb2) {
  const int m = blockIdx.x;
  const int row = idx[m];
  const float4 v = ((const float4*)(WE + (size_t)row * Ee))[threadIdx.x];
  ushort4 hi, lo;
  hi.x = f2b(v.x); lo.x = f2b(v.x - b2f(hi.x));
  hi.y = f2b(v.y); lo.y = f2b(v.y - b2f(hi.y));
  hi.z = f2b(v.z); lo.z = f2b(v.z - b2f(hi.z));
  hi.w = f2b(v.w); lo.w = f2b(v.w - b2f(hi.w));
  u16* d = emb2 + (size_t)m * 2048;
  ((ushort4*)d)[threadIdx.x] = hi;
  ((ushort4*)(d + Ee))[threadIdx.x] = lo;
}

// src[R][C] f32 -> dst[C][R<<dup] bf16 (transpose+cast hi); if dup, duplicate: [v | v]
__global__ __launch_bounds__(256)
void transpose_cast(const float* __restrict__ src, u16* __restrict__ dst,
                    int R, int C, int dup) {
  __shared__ float tile[32][33];
  const int bi = blockIdx.x;  // along C
  const int bj = blockIdx.y;  // along R
  const int tid = threadIdx.x;
  const int r  = tid >> 3;
  const int c4 = (tid & 7) * 4;
  float4 v = *(const float4*)(src + (size_t)(bj * 32 + r) * C + bi * 32 + c4);
  tile[r][c4 + 0] = v.x; tile[r][c4 + 1] = v.y;
  tile[r][c4 + 2] = v.z; tile[r][c4 + 3] = v.w;
  __syncthreads();
  const int RL = R << dup;
  ushort4 o;
  o.x = f2b(tile[c4 + 0][r]); o.y = f2b(tile[c4 + 1][r]);
  o.z = f2b(tile[c4 + 2][r]); o.w = f2b(tile[c4 + 3][r]);
  u16* d = dst + (size_t)(bi * 32 + r) * RL + bj * 32 + c4;
  *(ushort4*)d = o;
  if (dup) *(ushort4*)(d + R) = o;
}

// src[R][C] f32 -> hi[C][R], lo[C][R] bf16 (transpose + hi/lo split)
__global__ __launch_bounds__(256)
void transpose_cast_hilo(const float* __restrict__ src, u16* __restrict__ dhi,
                         u16* __restrict__ dlo, int R, int C) {
  __shared__ float tile[32][33];
  const int bi = blockIdx.x;  // along C
  const int bj = blockIdx.y;  // along R
  const int tid = threadIdx.x;
  const int r  = tid >> 3;
  const int c4 = (tid & 7) * 4;
  float4 v = *(const float4*)(src + (size_t)(bj * 32 + r) * C + bi * 32 + c4);
  tile[r][c4 + 0] = v.x; tile[r][c4 + 1] = v.y;
  tile[r][c4 + 2] = v.z; tile[r][c4 + 3] = v.w;
  __syncthreads();
  ushort4 oh, ol;
  #pragma unroll
  for (int j = 0; j < 4; ++j) {
    float x = tile[c4 + j][r];
    u16 h = f2b(x);
    ((u16*)&oh)[j] = h;
    ((u16*)&ol)[j] = f2b(x - b2f(h));
  }
  size_t off = (size_t)(bi * 32 + r) * R + bj * 32 + c4;
  *(ushort4*)(dhi + off) = oh;
  *(ushort4*)(dlo + off) = ol;
}

// h0[b] = [hi(start) | lo(start)] per batch row
__global__ __launch_bounds__(256)
void h0_init(const float* __restrict__ start, u16* __restrict__ hbuf) {
  const int b = blockIdx.x;
  #pragma unroll
  for (int j = 0; j < 8; ++j) {
    int n = threadIdx.x * 8 + j;
    float x = start[n];
    u16 hi = f2b(x);
    u16 lo = f2b(x - b2f(hi));
    hbuf[(size_t)b * 4096 + n] = hi;
    hbuf[(size_t)b * 4096 + 2048 + n] = lo;
  }
}

// ---------------- GEMM (m97-style 128x128 tile, BK=32, 4 waves) ----------------
// C[M x N] = A[M x K] * Bt[N x K]^T, bf16 inputs, f32 accum.
// MODE 0: out f32 at [row*N+col] + bias   (head GEMM -> logits in d_out)
// MODE 1: out bf16 at [(t*B+b)*N+col] + bias, row = b*T+t  (xproj, t-major)
// XCD-aware block swizzle (T1): nwg % 8 == 0 for both call sites.
template <int MODE>
__global__ __launch_bounds__(256, 2)
void gemm_bt(const u16* __restrict__ A, const u16* __restrict__ Bt,
             const float* __restrict__ bias, void* __restrict__ outp,
             int M, int N, int K) {
  __shared__ u16 ldsA[128 * 32];
  __shared__ u16 ldsB[128 * 32];
  const int tid = threadIdx.x;
  const int lane = tid & 63;
  const int w = tid >> 6;
  const int wr = w >> 1, wc = w & 1;

  const int nwg = gridDim.x * gridDim.y;
  const int lin = blockIdx.y * gridDim.x + blockIdx.x;
  const int swz = (lin & 7) * (nwg >> 3) + (lin >> 3);
  const int bm = swz % gridDim.x;
  const int bn = swz / gridDim.x;

  const int srow = w * 32 + (lane >> 2);
  const int scol = (lane & 3) * 8;
  const u16* a0 = A + (size_t)(bm * 128 + srow) * K + scol;
  const u16* b0 = Bt + (size_t)(bn * 128 + srow) * K + scol;
  u16* lA0 = ldsA + w * 1024;
  u16* lA1 = ldsA + w * 1024 + 512;
  u16* lB0 = ldsB + w * 1024;
  u16* lB1 = ldsB + w * 1024 + 512;

  f32x4 acc[4][4];
  #pragma unroll
  for (int m = 0; m < 4; ++m)
    #pragma unroll
    for (int n = 0; n < 4; ++n)
      acc[m][n] = (f32x4){0.f, 0.f, 0.f, 0.f};

  const int nk = K >> 5;
  for (int kt = 0; kt < nk; ++kt) {
    __syncthreads();
    const u16* ak = a0 + kt * 32;
    const u16* bk = b0 + kt * 32;
    gll16(ak, lA0);
    gll16(ak + 16 * (size_t)K, lA1);
    gll16(bk, lB0);
    gll16(bk + 16 * (size_t)K, lB1);
    __syncthreads();
    bf16x8 af[4], bfr[4];
    #pragma unroll
    for (int i = 0; i < 4; ++i) {
      af[i]  = *(const bf16x8*)&ldsA[(wr * 64 + i * 16 + (lane & 15)) * 32 + (lane >> 4) * 8];
      bfr[i] = *(const bf16x8*)&ldsB[(wc * 64 + i * 16 + (lane & 15)) * 32 + (lane >> 4) * 8];
    }
    #pragma unroll
    for (int m = 0; m < 4; ++m)
      #pragma unroll
      for (int n = 0; n < 4; ++n)
        acc[m][n] = __builtin_amdgcn_mfma_f32_16x16x32_bf16(af[m], bfr[n], acc[m][n], 0, 0, 0);
  }

  const int r0 = bm * 128 + wr * 64 + (lane >> 4) * 4;
  const int c0 = bn * 128 + wc * 64 + (lane & 15);
  #pragma unroll
  for (int n = 0; n < 4; ++n) {
    const int col = c0 + n * 16;
    const float bv = bias[col];
    #pragma unroll
    for (int m = 0; m < 4; ++m) {
      #pragma unroll
      for (int q = 0; q < 4; ++q) {
        const int row = r0 + m * 16 + q;
        float v = acc[m][n][q] + bv;
        if (MODE == 0) {
          ((float*)outp)[(size_t)row * N + col] = v;
        } else {
          const int b = row >> 9, t = row & 511;   // row = b*T + t
          ((u16*)outp)[((size_t)t * Bb + b) * N + col] = f2b(v);
        }
      }
    }
  }
}

// ---------------- persistent recurrence scan ----------------
// 256 blocks x 512 thr (8 waves), 1 block/CU (144KB LDS).
// Block bid: group g = bid>>6 owns batch rows [16g,16g+16); colg = bid&63 owns
// H-cols [colg*32, colg*32+32). Wh hi-part in LDS for all 512 steps; Wh lo in
// VGPRs. h (hi|lo) ping-pongs in global via sc1 (direct-to-L3) accesses.
//
// ALL barrier atomics are RELAXED (r5 change): agent-scope ACQ_REL/RELEASE/
// ACQUIRE compile to buffer_wbl2/buffer_inv (whole-L2 writeback/invalidate)
// on every block every step -- that maintenance, not RMW serialization, is the
// theory for r2-r4's ~10us/step barrier cost. Correctness without fences:
// all cross-block data (h, cnt, gn) moves through sc1 ops that complete at
// the L3 coherence point; __syncthreads drains vmcnt before arrival, and the
// poll-exit branch orders the subsequent sc1 h loads after the gn read.
// Monotonic counter + generation (no reset -> no reset race).
// Epilogue split across waves 0/1 (one 16-col frag each); xp prefetched at
// step top (barrier-independent).
__global__ __launch_bounds__(512, 2)
void rnn_scan(const u16* __restrict__ WhiT, const u16* __restrict__ WloT,
              const u16* __restrict__ xp, u16* __restrict__ hbuf,
              u16* __restrict__ hidden, unsigned* __restrict__ sync) {
  __shared__ u16 whi[65536];     // 128KB: frag(c2,kt) base (c2*64+kt)*512 u16
  __shared__ float red[4096];    // 16KB: 16 slots (frag0: w, frag1: 8+w) x 256 f32

  const int bid = blockIdx.x;
  const int g = bid >> 6;
  const int colg = bid & 63;
  const int rowbase = g * 16;
  const int col0 = colg * 32;
  const int tid = threadIdx.x;
  const int lane = tid & 63;
  const int w = tid >> 6;        // wave = K-slice index, 0..7

  // ---- preload Wh hi into LDS (one-time) ----
  for (int i = tid; i < 8192; i += 512) {
    const int ch = i & 3;
    const int cl = (i >> 2) & 15;
    const int kt = (i >> 6) & 63;
    const int c2 = (i >> 12) & 1;
    bf16x8 v = *(const bf16x8*)(WhiT + (size_t)(col0 + c2 * 16 + cl) * 2048 + kt * 32 + ch * 8);
    *(bf16x8*)&whi[(size_t)(c2 * 64 + kt) * 512 + ch * 128 + cl * 8] = v;
  }
  // ---- preload Wh lo into VGPRs (one-time): wave w covers ktG in [w*8, w*8+8) ----
  bf16x8 wlo[2][8];
  #pragma unroll
  for (int c2 = 0; c2 < 2; ++c2)
    #pragma unroll
    for (int kt = 0; kt < 8; ++kt)
      wlo[c2][kt] = *(const bf16x8*)(WloT + (size_t)(col0 + c2 * 16 + (lane & 15)) * 2048
                                     + (w * 8 + kt) * 32 + (lane >> 4) * 8);
  __syncthreads();

  unsigned* cnt = sync + g * 64;        // monotonic arrival counter
  unsigned* gn  = sync + g * 64 + 32;   // generation (last arriver stores t+1)
  bool dead = false;

  const int hrow = rowbase + (lane & 15);

  for (int t = 0; t < Tt; ++t) {
    const u16* hp = hbuf + (size_t)(t & 1) * (64 * 4096);
    u16*       hn = hbuf + (size_t)((t + 1) & 1) * (64 * 4096);

    // ---- xp prefetch for epilogue waves (independent of barrier/h) ----
    ushort4 xv = {0, 0, 0, 0};
    if (w < 2)
      xv = *(const ushort4*)(xp + ((size_t)t * Bb + hrow) * 2048 + col0 + w * 16 + (lane >> 4) * 4);

    // ---- batched h loads for this wave's K-slice: 16 x 16B, all in flight ----
    bf16x8 qh[8], ql[8];
    const u16* hb = hp + (size_t)hrow * 4096 + (lane >> 4) * 8;
    #pragma unroll
    for (int kt = 0; kt < 8; ++kt) {
      const u16* ph = hb + (w * 8 + kt) * 32;
      gload16_sc1(qh[kt], ph);           // hi half
      gload16_sc1(ql[kt], ph + 2048);    // lo half
    }
    asm volatile("s_waitcnt vmcnt(0)" ::: "memory");
    __builtin_amdgcn_sched_barrier(0);   // rule #18: pin MFMAs below the waitcnt

    f32x4 a0 = (f32x4){0.f, 0.f, 0.f, 0.f};
    f32x4 a1 = (f32x4){0.f, 0.f, 0.f, 0.f};
    #pragma unroll
    for (int kt = 0; kt < 8; ++kt) {
      const int ktG = w * 8 + kt;
      bf16x8 w0 = *(const bf16x8*)&whi[(size_t)(0 * 64 + ktG) * 512 + (lane >> 4) * 128 + (lane & 15) * 8];
      bf16x8 w1 = *(const bf16x8*)&whi[(size_t)(1 * 64 + ktG) * 512 + (lane >> 4) * 128 + (lane & 15) * 8];
      a0 = __builtin_amdgcn_mfma_f32_16x16x32_bf16(w0, qh[kt], a0, 0, 0, 0);
      a0 = __builtin_amdgcn_mfma_f32_16x16x32_bf16(w0, ql[kt], a0, 0, 0, 0);
      a0 = __builtin_amdgcn_mfma_f32_16x16x32_bf16(wlo[0][kt], qh[kt], a0, 0, 0, 0);
      a1 = __builtin_amdgcn_mfma_f32_16x16x32_bf16(w1, qh[kt], a1, 0, 0, 0);
      a1 = __builtin_amdgcn_mfma_f32_16x16x32_bf16(w1, ql[kt], a1, 0, 0, 0);
      a1 = __builtin_amdgcn_mfma_f32_16x16x32_bf16(wlo[1][kt], qh[kt], a1, 0, 0, 0);
    }

    // ---- K-reduce across waves: all waves export both frags ----
    *(f32x4*)&red[(w) * 256 + lane * 4]     = a0;   // frag0 bank: slots 0..7
    *(f32x4*)&red[(8 + w) * 256 + lane * 4] = a1;   // frag1 bank: slots 8..15
    __syncthreads();

    // ---- epilogue split: wave w<2 owns frag c2=w (cols col0+w*16 .. +16) ----
    if (w < 2) {
      f32x4 ac = (f32x4){0.f, 0.f, 0.f, 0.f};
      #pragma unroll
      for (int j = 0; j < 8; ++j)
        ac += *(const f32x4*)&red[(w * 8 + j) * 256 + lane * 4];
      const int cl0 = (lane >> 4) * 4;
      u16 hh[4], ll[4];
      #pragma unroll
      for (int qq = 0; qq < 4; ++qq) {
        float v = tanhf(ac[qq] + b2f(((const u16*)&xv)[qq]));
        hh[qq] = f2b(v); ll[qq] = f2b(v - b2f(hh[qq]));
      }
      u64 ph = pack4(hh[0], hh[1], hh[2], hh[3]);
      u64 pl = pack4(ll[0], ll[1], ll[2], ll[3]);
      u16* hd = hn + (size_t)hrow * 4096 + col0 + w * 16 + cl0;
      __hip_atomic_store((u64*)hd,          ph, __ATOMIC_RELAXED, __HIP_MEMORY_SCOPE_AGENT);
      __hip_atomic_store((u64*)(hd + 2048), pl, __ATOMIC_RELAXED, __HIP_MEMORY_SCOPE_AGENT);
      *(u64*)(hidden + ((size_t)hrow * Tt + t) * Hh + col0 + w * 16 + cl0) = ph;
    }

    // ---- group barrier: relaxed monotonic counter + generation flag ----
    __syncthreads();                    // drains vmcnt -> h stores complete at L3
    if (tid == 0) {
      unsigned old = __hip_atomic_fetch_add(cnt, 1u, __ATOMIC_RELAXED, __HIP_MEMORY_SCOPE_AGENT);
      if (old == (unsigned)(t * 64 + 63)) {
        __hip_atomic_store(gn, (unsigned)(t + 1), __ATOMIC_RELAXED, __HIP_MEMORY_SCOPE_AGENT);
      } else if (!dead) {
        unsigned polls = 0;
        while (__hip_atomic_load(gn, __ATOMIC_RELAXED, __HIP_MEMORY_SCOPE_AGENT) < (unsigned)(t + 1)) {
          if (++polls > 4000000u) { dead = true; break; }   // anti-hang escape
        }
      }
    }
    __syncthreads();
  }
}

// ---------------- loss ----------------

__global__ __launch_bounds__(256)
void row_nll(const float* __restrict__ logits, const int* __restrict__ tgt,
             float* __restrict__ nll) {
  const int m = blockIdx.x;
  const float4* rp = (const float4*)(logits + (size_t)m * Vv);
  const int tid = threadIdx.x;
  float4 v[8];
  float mx = -1e30f;
  #pragma unroll
  for (int j = 0; j < 8; ++j) {
    v[j] = rp[tid + j * 256];
    mx = fmaxf(mx, fmaxf(fmaxf(v[j].x, v[j].y), fmaxf(v[j].z, v[j].w)));
  }
  mx = wave_max(mx);
  __shared__ float sm[4], ss[4];
  const int w = tid >> 6;
  if ((tid & 63) == 0) sm[w] = mx;
  __syncthreads();
  mx = fmaxf(fmaxf(sm[0], sm[1]), fmaxf(sm[2], sm[3]));
  float s = 0.f;
  #pragma unroll
  for (int j = 0; j < 8; ++j)
    s += expf(v[j].x - mx) + expf(v[j].y - mx) + expf(v[j].z - mx) + expf(v[j].w - mx);
  s = wave_sum(s);
  if ((tid & 63) == 0) ss[w] = s;
  __syncthreads();
  if (tid == 0) {
    float S = ss[0] + ss[1] + ss[2] + ss[3];
    int tg = tgt[m];
    float o = 0.f;
    if (tg != -1) {
      float lt = logits[(size_t)m * Vv + tg];
      o = mx + logf(S) - lt;
    }
    nll[m] = o;
  }
}

__global__ __launch_bounds__(256)
void loss_reduce(const float* __restrict__ nll, const int* __restrict__ tgt,
                 float* __restrict__ out) {
  const int tid = threadIdx.x;
  float s = 0.f, c = 0.f;
  for (int i = tid; i < Bb * Tt; i += 256) {
    s += nll[i];
    c += (tgt[i] != -1) ? 1.f : 0.f;
  }
  s = wave_sum(s);
  c = wave_sum(c);
  __shared__ float as_[4], ac_[4];
  const int w = tid >> 6;
  if ((tid & 63) == 0) { as_[w] = s; ac_[w] = c; }
  __syncthreads();
  if (tid == 0) {
    float S = as_[0] + as_[1] + as_[2] + as_[3];
    float C = ac_[0] + ac_[1] + ac_[2] + ac_[3];
    out[0] = S / fmaxf(C, 1.f);
  }
}

// ---------------- launch ----------------

extern "C" void kernel_launch(void* const* d_in, const int* in_sizes, int n_in,
                              void* d_out, int out_size, void* d_ws, size_t ws_size,
                              hipStream_t stream) {
  const int*   idx    = (const int*)d_in[0];
  const int*   tgt    = (const int*)d_in[1];
  const float* W_E    = (const float*)d_in[2];
  const float* start  = (const float*)d_in[3];
  const float* W_xh   = (const float*)d_in[4];
  const float* b_xh   = (const float*)d_in[5];
  const float* W_head = (const float*)d_in[6];
  const float* b_head = (const float*)d_in[7];

  // workspace layout (~314 MB). emb2 (dead after GEMM1) aliases hidden.
  char* ws = (char*)d_ws;
  u16*      emb2   = (u16*)(ws);                                  // 32768x2048 bf16 = 128MB
  u16*      hidden = (u16*)(ws);                                  // 32768x2048 bf16 (alias)
  u16*      xproj  = (u16*)(ws + (size_t)128 * 1024 * 1024);      // [T][B][H] bf16 = 128MB
  u16*      WheadT = (u16*)(ws + (size_t)256 * 1024 * 1024);      // 8192x2048 bf16 = 32MB
  u16*      WhiT   = (u16*)(ws + (size_t)288 * 1024 * 1024);      // 2048x2048 bf16 = 8MB
  u16*      WloT   = (u16*)(ws + (size_t)296 * 1024 * 1024);      // 2048x2048 bf16 = 8MB
  u16*      WxT2   = (u16*)(ws + (size_t)304 * 1024 * 1024);      // 2048x2048 bf16 = 8MB
  u16*      hbuf   = (u16*)(ws + (size_t)312 * 1024 * 1024);      // 2x64x4096 bf16 = 1MB
  float*    nll    = (float*)(ws + (size_t)313 * 1024 * 1024);    // 32768 f32 = 128KB
  unsigned* sync   = (unsigned*)(ws + (size_t)313 * 1024 * 1024 + 128 * 1024); // 1KB

  embed_cast<<<Bb * Tt, 256, 0, stream>>>(W_E, idx, emb2);
  transpose_cast<<<dim3(Hh / 32, Ee / 32), 256, 0, stream>>>(W_xh, WxT2, Ee, Hh, 1);
  transpose_cast_hilo<<<dim3(Hh / 32, Hh / 32), 256, 0, stream>>>(W_xh + (size_t)Ee * Hh, WhiT, WloT, Hh, Hh);
  transpose_cast<<<dim3(Vv / 32, Hh / 32), 256, 0, stream>>>(W_head, WheadT, Hh, Vv, 0);
  h0_init<<<Bb, 256, 0, stream>>>(start, hbuf);
  hipMemsetAsync(sync, 0, 1024, stream);

  // xproj = [emb_hi|emb_lo] @ [Wx;Wx] + b_xh   (K=2048 effective)
  gemm_bt<1><<<dim3(256, 16), 256, 0, stream>>>(emb2, WxT2, b_xh, xproj, Bb * Tt, Hh, 2048);

  // persistent scan: 256 blocks (1/CU), 512 threads, Wh resident in LDS+VGPR
  rnn_scan<<<256, 512, 0, stream>>>(WhiT, WloT, xproj, hbuf, hidden, sync);

  // logits = hidden @ W_head + b_head  -> d_out
  gemm_bt<0><<<dim3(256, 64), 256, 0, stream>>>(hidden, WheadT, b_head, d_out, Bb * Tt, Vv, 2048);

  row_nll<<<Bb * Tt, 256, 0, stream>>>((const float*)d_out, tgt, nll);
  loss_reduce<<<1, 256, 0, stream>>>(nll, tgt, (float*)d_out + ((size_t)out_size - 1));
}